// Round 9
// baseline (177.581 us; speedup 1.0000x reference)
//
#include <hip/hip_runtime.h>
#include <hip/hip_bf16.h>

constexpr int B  = 128;
constexpr int LQ = 128;
constexpr int LS = 256;
constexpr int D  = 1024;
constexpr int SD = 256;
constexpr float EPS = 1e-8f;

typedef __attribute__((ext_vector_type(8))) __bf16 bf16x8;
typedef __attribute__((ext_vector_type(4))) float f32x4;

__device__ inline ushort f2bf(float f) {
    union { float f; uint u; } v{f};
    uint r = v.u + 0x7fffu + ((v.u >> 16) & 1u);   // RNE
    return (ushort)(r >> 16);
}
__device__ inline float bf2f(ushort u) {
    union { uint u; float f; } v{(uint)u << 16};
    return v.f;
}
__device__ inline uint4 pack8(float4 a, float4 b) {
    union { ushort us[8]; uint4 u4; } r;
    r.us[0]=f2bf(a.x); r.us[1]=f2bf(a.y); r.us[2]=f2bf(a.z); r.us[3]=f2bf(a.w);
    r.us[4]=f2bf(b.x); r.us[5]=f2bf(b.y); r.us[6]=f2bf(b.z); r.us[7]=f2bf(b.w);
    return r.u4;
}
// 128B-row LDS tiles (64 bf16): XOR-swizzle bank fix
__device__ inline int swz(int row, int kbyte) {
    return row * 128 + (kbyte ^ ((row & 7) << 4));
}
__device__ inline bf16x8 lds_frag(const ushort* base, int row, int kk, int lane) {
    int kbyte = kk * 64 + (lane >> 4) * 16;
    return *(const bf16x8*)((const char*)base + swz(row, kbyte));
}
// 512B-row LDS tiles (256 bf16): same XOR pattern
__device__ inline int swz512(int row, int kbyte) {
    return row * 512 + (kbyte ^ ((row & 7) << 4));
}
__device__ inline f32x4 mfma16(bf16x8 a, bf16x8 b, f32x4 c) {
    return __builtin_amdgcn_mfma_f32_16x16x32_bf16(a, b, c, 0, 0, 0);
}

// =====================================================================
// streaming converters (all HBM-bound, 8 elems/thread)
// =====================================================================
__global__ __launch_bounds__(256) void wconv_kernel(
    const float* __restrict__ W, ushort* __restrict__ Wb)
{
    size_t i = ((size_t)blockIdx.x * 256 + threadIdx.x) * 8;
    float4 a = *(const float4*)(W + i);
    float4 b = *(const float4*)(W + i + 4);
    *(uint4*)(Wb + i) = pack8(a, b);
}

__global__ __launch_bounds__(256) void qmconv_kernel(
    const float* __restrict__ query, const float* __restrict__ mat,
    ushort* __restrict__ qm)
{
    size_t i = ((size_t)blockIdx.x * 256 + threadIdx.x) * 8;
    float4 q1 = *(const float4*)(query + i), q2 = *(const float4*)(query + i + 4);
    float4 m1 = *(const float4*)(mat + i),   m2 = *(const float4*)(mat + i + 4);
    float4 p1{q1.x*m1.x, q1.y*m1.y, q1.z*m1.z, q1.w*m1.w};
    float4 p2{q2.x*m2.x, q2.y*m2.y, q2.z*m2.z, q2.w*m2.w};
    *(uint4*)(qm + i) = pack8(p1, p2);
}

__global__ __launch_bounds__(256) void cconv_kernel(
    const float* __restrict__ ctx, ushort* __restrict__ ctxB)
{
    size_t i = ((size_t)blockIdx.x * 256 + threadIdx.x) * 8;
    float4 a = *(const float4*)(ctx + i);
    float4 b = *(const float4*)(ctx + i + 4);
    *(uint4*)(ctxB + i) = pack8(a, b);
}

// =====================================================================
// gemmA: S = leaky( qm[128q][.] . ctxB[64s][.]^T ); col-l2norm over q;
// E = exp(S*inv*smooth) bf16 (LDS-gathered, coalesced store).
// Grid 512 = (b x 4 s-tiles), XCD-swizzled. 512 thr, 8 waves 2q x 4s.
// BM=128 BN=64 BK=64, double-buffered LDS. All-bf16 operands.
// =====================================================================
__global__ __launch_bounds__(512) void gemmA_kernel(
    const ushort* __restrict__ qm, const ushort* __restrict__ ctxB,
    const int* __restrict__ smooth_p, ushort* __restrict__ E)
{
    const int bid = blockIdx.x;
    const int xcd = bid & 7, idx = bid >> 3;
    const int b  = xcd * 16 + (idx >> 2);
    const int n0 = (idx & 3) * 64;        // s-offset
    __shared__ ushort As[2][128 * 64];    // 32 KB
    __shared__ ushort Bs[2][64 * 64];     // 16 KB
    __shared__ float colssP[2][64];
    __shared__ float invsm[64];
    ushort* Et = (ushort*)As;             // epilogue alias: 128x72 = 18 KB
    const int t = threadIdx.x;
    const int wv = t >> 6, l = t & 63;
    const int wq = wv >> 2, wsv = wv & 3;

    const ushort* Ab = qm   + (size_t)b * LQ * D;
    const ushort* Cb = ctxB + ((size_t)b * LS + n0) * D;
    const int r0 = t >> 3, k8 = (t & 7) * 8;

    f32x4 acc[4] = {};
    uint4 a0, a1, b0;

    // prologue: stage tile 0
    a0 = *(const uint4*)(Ab + (size_t)r0 * D + k8);
    a1 = *(const uint4*)(Ab + (size_t)(r0 + 64) * D + k8);
    b0 = *(const uint4*)(Cb + (size_t)r0 * D + k8);
    *(uint4*)((char*)As[0] + swz(r0, k8 * 2))      = a0;
    *(uint4*)((char*)As[0] + swz(r0 + 64, k8 * 2)) = a1;
    *(uint4*)((char*)Bs[0] + swz(r0, k8 * 2))      = b0;
    __syncthreads();

    int cur = 0;
#pragma unroll 1
    for (int ks = 0; ks < 15; ++ks) {
        const int k0 = (ks + 1) * 64;
        a0 = *(const uint4*)(Ab + (size_t)r0 * D + k0 + k8);
        a1 = *(const uint4*)(Ab + (size_t)(r0 + 64) * D + k0 + k8);
        b0 = *(const uint4*)(Cb + (size_t)r0 * D + k0 + k8);
#pragma unroll
        for (int kk = 0; kk < 2; ++kk) {
            bf16x8 bfr = lds_frag(Bs[cur], wsv * 16 + (l & 15), kk, l);
#pragma unroll
            for (int i = 0; i < 4; ++i) {
                bf16x8 af = lds_frag(As[cur], wq * 64 + i * 16 + (l & 15), kk, l);
                acc[i] = mfma16(af, bfr, acc[i]);
            }
        }
        *(uint4*)((char*)As[cur ^ 1] + swz(r0, k8 * 2))      = a0;
        *(uint4*)((char*)As[cur ^ 1] + swz(r0 + 64, k8 * 2)) = a1;
        *(uint4*)((char*)Bs[cur ^ 1] + swz(r0, k8 * 2))      = b0;
        __syncthreads();
        cur ^= 1;
    }
#pragma unroll
    for (int kk = 0; kk < 2; ++kk) {
        bf16x8 bfr = lds_frag(Bs[cur], wsv * 16 + (l & 15), kk, l);
#pragma unroll
        for (int i = 0; i < 4; ++i) {
            bf16x8 af = lds_frag(As[cur], wq * 64 + i * 16 + (l & 15), kk, l);
            acc[i] = mfma16(af, bfr, acc[i]);
        }
    }

    // epilogue: leaky + column sumsq (over 128 q) -> invsm -> E=exp
    float csum = 0.f;
#pragma unroll
    for (int i = 0; i < 4; ++i)
#pragma unroll
        for (int r = 0; r < 4; ++r) {
            float v = acc[i][r];
            v = v >= 0.f ? v : 0.1f * v;
            acc[i][r] = v;
            csum += v * v;
        }
    csum += __shfl_xor(csum, 16);
    csum += __shfl_xor(csum, 32);
    if (l < 16) colssP[wq][wsv * 16 + l] = csum;
    __syncthreads();   // also: all MFMA done -> As reusable as Et
    const float sm = (float)(*smooth_p);
    if (t < 64) invsm[t] = sm / (sqrtf(colssP[0][t] + colssP[1][t]) + EPS);
    __syncthreads();
    const float invc = invsm[wsv * 16 + (l & 15)];
#pragma unroll
    for (int i = 0; i < 4; ++i)
#pragma unroll
        for (int r = 0; r < 4; ++r) {
            int row = wq * 64 + i * 16 + (l >> 4) * 4 + r;
            Et[row * 72 + wsv * 16 + (l & 15)] = f2bf(__expf(acc[i][r] * invc));
        }
    __syncthreads();
    // coalesced E store: 1024 uint4 chunks, 2/thread
    ushort* Eg = E + (size_t)b * LQ * LS + n0;
#pragma unroll
    for (int j = 0; j < 2; ++j) {
        int c = t + j * 512;
        int row = c >> 3, s8 = (c & 7) * 8;
        *(uint4*)(Eg + (size_t)row * LS + s8) = *(const uint4*)(Et + row * 72 + s8);
    }
}

// =====================================================================
// pv: wctx[128q][512d-half] = (E . ctxB^T) * (1/rowsum(E)); rowss partials.
// Grid 256 = (b x 2 dh), XCD-swizzled. 512 thr, 8 waves 2q x 4d.
// B staged from bf16 ctxB via in-LDS transpose into padded Bs[64][264].
// =====================================================================
__global__ __launch_bounds__(512) void pv_kernel(
    const ushort* __restrict__ E, const ushort* __restrict__ ctxB,
    ushort* __restrict__ wctx, float* __restrict__ rowssP)
{
    const int bid = blockIdx.x;
    const int xcd = bid & 7, idx = bid >> 3;
    const int b  = xcd * 16 + (idx >> 1);
    const int dh = idx & 1;
    const int dglob0 = dh * 512;

    __shared__ ushort Es[128 * 256];       // 64 KB swz512
    __shared__ ushort Bs[64 * 264];        // 33 KB padded [d][s+8]
    __shared__ float rsumL[128];
    __shared__ float rinv[128];
    __shared__ float rowssL[128][4];

    const int t = threadIdx.x;
    const int wv = t >> 6, l = t & 63;
    const int wq = wv >> 2, wd = wv & 3;

    // ---- stage E (128q x 256s) + per-row exp sums ----
    const ushort* Eb = E + (size_t)b * LQ * LS;
    const int cc = t & 31, rr = t >> 5;    // col-chunk, row-base
    float part[8];
#pragma unroll
    for (int p = 0; p < 8; ++p) {
        int row = rr + p * 16;
        uint4 v = *(const uint4*)(Eb + (size_t)row * LS + cc * 8);
        *(uint4*)((char*)Es + swz512(row, cc * 16)) = v;
        const ushort* us = (const ushort*)&v;
        float s = 0.f;
#pragma unroll
        for (int j = 0; j < 8; ++j) s += bf2f(us[j]);
        part[p] = s;
    }
    rowssL[t >> 2][t & 3] = 0.f;
#pragma unroll
    for (int p = 0; p < 8; ++p) {
        float s = part[p];
        s += __shfl_xor(s, 1);  s += __shfl_xor(s, 2);
        s += __shfl_xor(s, 4);  s += __shfl_xor(s, 8);
        s += __shfl_xor(s, 16);
        if ((l & 31) == 0) rsumL[rr + p * 16] = s;
    }

    // ---- prefetch ctxB tile dt=0 ----
    const ushort* Cb = ctxB + (size_t)b * LS * D + dglob0;
    const int sr = t >> 4, c4 = (t & 15) * 4;   // staging: s-row base, d-col
    uint2 cr[8];
#pragma unroll
    for (int p = 0; p < 8; ++p)
        cr[p] = *(const uint2*)(Cb + (size_t)(p * 32 + sr) * D + c4);

    __syncthreads();   // Es + rsumL visible
    if (t < 128) rinv[t] = 1.0f / rsumL[t];

    // ---- write Bs dt=0 (transpose scatter into padded tile) ----
#pragma unroll
    for (int p = 0; p < 8; ++p) {
        int s = p * 32 + sr;
        const ushort* us = (const ushort*)&cr[p];
        Bs[(c4 + 0) * 264 + s] = us[0];
        Bs[(c4 + 1) * 264 + s] = us[1];
        Bs[(c4 + 2) * 264 + s] = us[2];
        Bs[(c4 + 3) * 264 + s] = us[3];
    }
    __syncthreads();   // Bs + rinv visible

    ushort* Ob = wctx + (size_t)b * LQ * D + dglob0;

#pragma unroll 1
    for (int dt = 0; dt < 8; ++dt) {
        // issue next-tile loads (hide under MFMA)
        if (dt < 7) {
#pragma unroll
            for (int p = 0; p < 8; ++p)
                cr[p] = *(const uint2*)(Cb + (size_t)(p * 32 + sr) * D + (dt + 1) * 64 + c4);
        }
        // MFMA: out rows wq*64+i*16.., cols dt*64 + wd*16..
        f32x4 acc[4] = {};
#pragma unroll
        for (int kk = 0; kk < 8; ++kk) {
            const ushort* bp = Bs + (wd * 16 + (l & 15)) * 264 + kk * 32 + (l >> 4) * 8;
            bf16x8 bfr = *(const bf16x8*)bp;
#pragma unroll
            for (int i = 0; i < 4; ++i) {
                bf16x8 af = *(const bf16x8*)((const char*)Es +
                    swz512(wq * 64 + i * 16 + (l & 15), kk * 64 + (l >> 4) * 16));
                acc[i] = mfma16(af, bfr, acc[i]);
            }
        }
        // epilogue: normalize, rowss partial, write
#pragma unroll
        for (int i = 0; i < 4; ++i)
#pragma unroll
            for (int r = 0; r < 4; ++r) {
                int row = wq * 64 + i * 16 + (l >> 4) * 4 + r;
                float wval = acc[i][r] * rinv[row];
                float p2 = wval * wval;
                p2 += __shfl_xor(p2, 1); p2 += __shfl_xor(p2, 2);
                p2 += __shfl_xor(p2, 4); p2 += __shfl_xor(p2, 8);
                if ((l & 15) == 0) rowssL[row][wd] += p2;
                Ob[(size_t)row * D + dt * 64 + wd * 16 + (l & 15)] = f2bf(wval);
            }
        __syncthreads();   // Bs consumed
        if (dt < 7) {
#pragma unroll
            for (int p = 0; p < 8; ++p) {
                int s = p * 32 + sr;
                const ushort* us = (const ushort*)&cr[p];
                Bs[(c4 + 0) * 264 + s] = us[0];
                Bs[(c4 + 1) * 264 + s] = us[1];
                Bs[(c4 + 2) * 264 + s] = us[2];
                Bs[(c4 + 3) * 264 + s] = us[3];
            }
            __syncthreads();
        }
    }
    if (t < 128)
        rowssP[(size_t)b * 256 + dh * 128 + t] =
            rowssL[t][0] + rowssL[t][1] + rowssL[t][2] + rowssL[t][3];
}

// =====================================================================
// gemm3+finalnorm: out[b][q][k] = l2norm_k( sum_d sr[q][d]*Wb[k][d] + b[k] )
// sr on the fly: (query - wctx*invq)^2 with invq from rowssP halves.
// BM=64(q) BN=256 BK=64. 512 thr, 8 waves 2x4.
// =====================================================================
__global__ __launch_bounds__(512) void gemm3_kernel(
    const ushort* __restrict__ wctx, const float* __restrict__ query,
    const float* __restrict__ rowssP, const ushort* __restrict__ Wb,
    const float* __restrict__ bias, float* __restrict__ out)
{
    const int m0 = blockIdx.x * 64;
    const int b  = blockIdx.y;
    __shared__ ushort As[64 * 64];
    __shared__ ushort Bs[256 * 64];
    __shared__ float red[64][4];
    __shared__ float invr[64];
    const int t = threadIdx.x;
    const int w = t >> 6, l = t & 63;
    const int wm = (w >> 2) * 32, wn = (w & 3) * 64;

    const int arow = t >> 3, ako = (t & 7) * 8;
    const float r0v = rowssP[(size_t)b * 256 + m0 + arow];
    const float r1v = rowssP[(size_t)b * 256 + 128 + m0 + arow];
    const float ivq = 1.0f / (sqrtf(r0v + r1v) + EPS);
    const float* Qp  = query + ((size_t)b * LQ + m0 + arow) * D + ako;
    const ushort* Wp = wctx  + ((size_t)b * LQ + m0 + arow) * D + ako;

    f32x4 acc[2][4] = {};

    for (int k0 = 0; k0 < D; k0 += 64) {
        if (k0) __syncthreads();
        {   // A: sr on the fly
            uint4 wu = *(const uint4*)(Wp + k0);
            float4 q1 = *(const float4*)(Qp + k0);
            float4 q2 = *(const float4*)(Qp + k0 + 4);
            float d0 = q1.x - bf2f((ushort)(wu.x & 0xffff)) * ivq;
            float d1 = q1.y - bf2f((ushort)(wu.x >> 16))    * ivq;
            float d2 = q1.z - bf2f((ushort)(wu.y & 0xffff)) * ivq;
            float d3 = q1.w - bf2f((ushort)(wu.y >> 16))    * ivq;
            float d4 = q2.x - bf2f((ushort)(wu.z & 0xffff)) * ivq;
            float d5 = q2.y - bf2f((ushort)(wu.z >> 16))    * ivq;
            float d6 = q2.z - bf2f((ushort)(wu.w & 0xffff)) * ivq;
            float d7 = q2.w - bf2f((ushort)(wu.w >> 16))    * ivq;
            float4 s1{d0*d0, d1*d1, d2*d2, d3*d3};
            float4 s2{d4*d4, d5*d5, d6*d6, d7*d7};
            *(uint4*)((char*)As + swz(arow, ako * 2)) = pack8(s1, s2);
        }
#pragma unroll
        for (int j = 0; j < 4; ++j) {   // B: Wb
            int c = t + j * 512;
            int row = c >> 3, ko = (c & 7) * 8;
            *(uint4*)((char*)Bs + swz(row, ko * 2)) =
                *(const uint4*)(Wb + (size_t)row * D + k0 + ko);
        }
        __syncthreads();
#pragma unroll
        for (int kk = 0; kk < 2; ++kk) {
            bf16x8 af[2], bfr[4];
#pragma unroll
            for (int i = 0; i < 2; ++i) af[i] = lds_frag(As, wm + i * 16 + (l & 15), kk, l);
#pragma unroll
            for (int n = 0; n < 4; ++n) bfr[n] = lds_frag(Bs, wn + n * 16 + (l & 15), kk, l);
#pragma unroll
            for (int i = 0; i < 2; ++i)
#pragma unroll
                for (int n = 0; n < 4; ++n) acc[i][n] = mfma16(af[i], bfr[n], acc[i][n]);
        }
    }
#pragma unroll
    for (int n = 0; n < 4; ++n) {
        float bv = bias[wn + n * 16 + (l & 15)];
#pragma unroll
        for (int i = 0; i < 2; ++i)
#pragma unroll
            for (int r = 0; r < 4; ++r) acc[i][n][r] += bv;
    }
#pragma unroll
    for (int i = 0; i < 2; ++i)
#pragma unroll
        for (int r = 0; r < 4; ++r) {
            float p = 0.f;
#pragma unroll
            for (int n = 0; n < 4; ++n) p += acc[i][n][r] * acc[i][n][r];
#pragma unroll
            for (int off = 1; off < 16; off <<= 1) p += __shfl_xor(p, off);
            int rowl = wm + i * 16 + (l >> 4) * 4 + r;
            if ((l & 15) == 0) red[rowl][w & 3] = p;
        }
    __syncthreads();
    if (t < 64) {
        float s = red[t][0] + red[t][1] + red[t][2] + red[t][3];
        invr[t] = 1.0f / (sqrtf(s) + EPS);
    }
    __syncthreads();
    float* Ob = out + ((size_t)b * LQ + m0) * SD;
#pragma unroll
    for (int i = 0; i < 2; ++i)
#pragma unroll
        for (int r = 0; r < 4; ++r) {
            int rowl = wm + i * 16 + (l >> 4) * 4 + r;
            float iv = invr[rowl];
#pragma unroll
            for (int n = 0; n < 4; ++n) {
                int col = wn + n * 16 + (l & 15);
                Ob[(size_t)rowl * SD + col] = acc[i][n][r] * iv;
            }
        }
}

// =====================================================================
extern "C" void kernel_launch(void* const* d_in, const int* in_sizes, int n_in,
                              void* d_out, int out_size, void* d_ws, size_t ws_size,
                              hipStream_t stream)
{
    const float* query  = (const float*)d_in[0];
    const float* ctx    = (const float*)d_in[1];
    const float* mat    = (const float*)d_in[2];
    const float* W      = (const float*)d_in[3];
    const float* bias   = (const float*)d_in[4];
    const int*   smooth = (const int*)d_in[5];
    float* out = (float*)d_out;

    char* ws = (char*)d_ws;
    ushort* ctxB   = (ushort*)ws;                                   // 64 MiB
    ushort* qm     = (ushort*)(ws + (size_t)64 * 1024 * 1024);      // 32 MiB
    ushort* wctx   = qm;   // overlay: qm dead after gemmA, wctx written by pv
    ushort* E      = (ushort*)(ws + (size_t)96 * 1024 * 1024);      //  8 MiB
    ushort* Wb     = (ushort*)(ws + (size_t)104 * 1024 * 1024);     // 0.5 MiB
    float*  rowssP = (float*)(ws + (size_t)(104 * 1024 + 512) * 1024); // 128 KiB

    wconv_kernel<<<dim3(SD * D / (256 * 8)), 256, 0, stream>>>(W, Wb);
    qmconv_kernel<<<dim3((size_t)B * LQ * D / (256 * 8)), 256, 0, stream>>>(query, mat, qm);
    cconv_kernel<<<dim3((size_t)B * LS * D / (256 * 8)), 256, 0, stream>>>(ctx, ctxB);
    gemmA_kernel<<<dim3(512), 512, 0, stream>>>(qm, ctxB, smooth, E);
    pv_kernel<<<dim3(256), 512, 0, stream>>>(E, ctxB, wctx, rowssP);
    gemm3_kernel<<<dim3(2, B), 512, 0, stream>>>(wctx, query, rowssP, Wb, bias, out);
}

// Round 10
// 150.189 us; speedup vs baseline: 1.1824x; 1.1824x over previous
//
#include <hip/hip_runtime.h>
#include <hip/hip_bf16.h>

constexpr int B  = 128;
constexpr int LQ = 128;
constexpr int LS = 256;
constexpr int D  = 1024;
constexpr int SD = 256;
constexpr float EPS = 1e-8f;

typedef __attribute__((ext_vector_type(8))) __bf16 bf16x8;
typedef __attribute__((ext_vector_type(4))) float f32x4;

__device__ inline ushort f2bf(float f) {
    union { float f; uint u; } v{f};
    uint r = v.u + 0x7fffu + ((v.u >> 16) & 1u);   // RNE
    return (ushort)(r >> 16);
}
__device__ inline float bf2f(ushort u) {
    union { uint u; float f; } v{(uint)u << 16};
    return v.f;
}
__device__ inline uint4 pack8(float4 a, float4 b) {
    union { ushort us[8]; uint4 u4; } r;
    r.us[0]=f2bf(a.x); r.us[1]=f2bf(a.y); r.us[2]=f2bf(a.z); r.us[3]=f2bf(a.w);
    r.us[4]=f2bf(b.x); r.us[5]=f2bf(b.y); r.us[6]=f2bf(b.z); r.us[7]=f2bf(b.w);
    return r.u4;
}
// 128B-row LDS tiles (64 bf16): XOR-swizzle bank fix
__device__ inline int swz(int row, int kbyte) {
    return row * 128 + (kbyte ^ ((row & 7) << 4));
}
__device__ inline bf16x8 lds_frag(const ushort* base, int row, int kk, int lane) {
    int kbyte = kk * 64 + (lane >> 4) * 16;
    return *(const bf16x8*)((const char*)base + swz(row, kbyte));
}
// 512B-row LDS tiles (256 bf16): same XOR pattern
__device__ inline int swz512(int row, int kbyte) {
    return row * 512 + (kbyte ^ ((row & 7) << 4));
}
__device__ inline f32x4 mfma16(bf16x8 a, bf16x8 b, f32x4 c) {
    return __builtin_amdgcn_mfma_f32_16x16x32_bf16(a, b, c, 0, 0, 0);
}

// =====================================================================
// Wb (bf16) <- W fp32
// =====================================================================
__global__ __launch_bounds__(256) void wconv_kernel(
    const float* __restrict__ W, ushort* __restrict__ Wb)
{
    size_t i = ((size_t)blockIdx.x * 256 + threadIdx.x) * 8;
    float4 a = *(const float4*)(W + i);
    float4 b = *(const float4*)(W + i + 4);
    *(uint4*)(Wb + i) = pack8(a, b);
}

// =====================================================================
// gemmA: per block (b, s-half of 128):
//   A-stage: qm = query*matrix fp32 -> bf16 (fused)
//   S = leaky(qm . ctx^T); col-l2norm over q (all 128 in-block);
//   E = exp(S*inv*smooth) bf16 (LDS-gathered, coalesced store).
// Grid 256 = (b x 2 s-halves), XCD-swizzled. 512 thr, 8 waves 2q x 4s.
// BM=128 BN=128 BK=64, double-buffered LDS (64 KB).
// No softmax max-pass: |x| <= smooth after l2norm.
// =====================================================================
__global__ __launch_bounds__(512) void gemmA_kernel(
    const float* __restrict__ query, const float* __restrict__ mat,
    const float* __restrict__ ctx, const int* __restrict__ smooth_p,
    ushort* __restrict__ E)
{
    const int bid = blockIdx.x;            // 256 blocks
    const int xcd = bid & 7, idx = bid >> 3;
    const int b  = xcd * 16 + (idx >> 1);
    const int n0 = (idx & 1) * 128;        // s-offset
    __shared__ ushort SH[4][128 * 64];     // As0,As1,Bs0,Bs1 (64 KB)
    __shared__ float colssP[2][128];
    __shared__ float invsm[128];
    ushort* Et = &SH[0][0];                // epilogue alias: 128 x 136

    const int t = threadIdx.x;
    const int wv = t >> 6, l = t & 63;
    const int wq = wv >> 2, wsv = wv & 3;

    const float* Qb = query + (size_t)b * LQ * D;
    const float* Mb = mat   + (size_t)b * LQ * D;
    const float* Cb = ctx   + ((size_t)b * LS + n0) * D;
    const int r0 = t >> 3, k8 = (t & 7) * 8;

    f32x4 acc[4][2] = {};
    float4 q0,q1,q2,q3, m0,m1,m2,m3, c0,c1,c2,c3;

    // ---- load tile k0 into registers ----
    auto loadT = [&](int k0) {
        const float* qp = Qb + (size_t)r0 * D + k0 + k8;
        const float* mp = Mb + (size_t)r0 * D + k0 + k8;
        q0 = *(const float4*)qp; q1 = *(const float4*)(qp + 4);
        m0 = *(const float4*)mp; m1 = *(const float4*)(mp + 4);
        qp += (size_t)64 * D;  mp += (size_t)64 * D;
        q2 = *(const float4*)qp; q3 = *(const float4*)(qp + 4);
        m2 = *(const float4*)mp; m3 = *(const float4*)(mp + 4);
        const float* cp = Cb + (size_t)r0 * D + k0 + k8;
        c0 = *(const float4*)cp; c1 = *(const float4*)(cp + 4);
        cp += (size_t)64 * D;
        c2 = *(const float4*)cp; c3 = *(const float4*)(cp + 4);
    };
    // ---- pack + store registers into LDS buffer ----
    auto storeT = [&](int buf) {
        float4 p1{q0.x*m0.x, q0.y*m0.y, q0.z*m0.z, q0.w*m0.w};
        float4 p2{q1.x*m1.x, q1.y*m1.y, q1.z*m1.z, q1.w*m1.w};
        *(uint4*)((char*)&SH[buf][0] + swz(r0, k8 * 2)) = pack8(p1, p2);
        float4 p3{q2.x*m2.x, q2.y*m2.y, q2.z*m2.z, q2.w*m2.w};
        float4 p4{q3.x*m3.x, q3.y*m3.y, q3.z*m3.z, q3.w*m3.w};
        *(uint4*)((char*)&SH[buf][0] + swz(r0 + 64, k8 * 2)) = pack8(p3, p4);
        *(uint4*)((char*)&SH[2 + buf][0] + swz(r0, k8 * 2))      = pack8(c0, c1);
        *(uint4*)((char*)&SH[2 + buf][0] + swz(r0 + 64, k8 * 2)) = pack8(c2, c3);
    };
    // ---- MFMA on buffer ----
    auto mfmaT = [&](int buf) {
#pragma unroll
        for (int kk = 0; kk < 2; ++kk) {
            bf16x8 bfr0 = lds_frag(&SH[2 + buf][0], wsv * 32 + (l & 15), kk, l);
            bf16x8 bfr1 = lds_frag(&SH[2 + buf][0], wsv * 32 + 16 + (l & 15), kk, l);
#pragma unroll
            for (int i = 0; i < 4; ++i) {
                bf16x8 af = lds_frag(&SH[buf][0], wq * 64 + i * 16 + (l & 15), kk, l);
                acc[i][0] = mfma16(af, bfr0, acc[i][0]);
                acc[i][1] = mfma16(af, bfr1, acc[i][1]);
            }
        }
    };

    loadT(0);
    storeT(0);
    __syncthreads();
    int cur = 0;
#pragma unroll 1
    for (int ks = 0; ks < 15; ++ks) {
        loadT((ks + 1) * 64);
        mfmaT(cur);
        storeT(cur ^ 1);
        __syncthreads();
        cur ^= 1;
    }
    mfmaT(cur);

    // ---- epilogue: leaky + col sumsq -> invsm -> E = exp ----
#pragma unroll
    for (int n = 0; n < 2; ++n) {
        float csum = 0.f;
#pragma unroll
        for (int i = 0; i < 4; ++i)
#pragma unroll
            for (int r = 0; r < 4; ++r) {
                float v = acc[i][n][r];
                v = v >= 0.f ? v : 0.1f * v;
                acc[i][n][r] = v;
                csum += v * v;
            }
        csum += __shfl_xor(csum, 16);
        csum += __shfl_xor(csum, 32);
        if (l < 16) colssP[wq][wsv * 32 + n * 16 + l] = csum;
    }
    __syncthreads();   // also: all MFMA reads done -> SH reusable as Et
    const float sm = (float)(*smooth_p);
    if (t < 128) invsm[t] = sm / (sqrtf(colssP[0][t] + colssP[1][t]) + EPS);
    __syncthreads();
#pragma unroll
    for (int n = 0; n < 2; ++n) {
        const float invc = invsm[wsv * 32 + n * 16 + (l & 15)];
#pragma unroll
        for (int i = 0; i < 4; ++i)
#pragma unroll
            for (int r = 0; r < 4; ++r) {
                int row = wq * 64 + i * 16 + (l >> 4) * 4 + r;
                Et[row * 136 + wsv * 32 + n * 16 + (l & 15)] =
                    f2bf(__expf(acc[i][n][r] * invc));
            }
    }
    __syncthreads();
    // coalesced E store: 128 rows x 16 uint4 chunks = 2048, 4/thread
    ushort* Eg = E + (size_t)b * LQ * LS + n0;
#pragma unroll
    for (int j = 0; j < 4; ++j) {
        int c = t + j * 512;
        int row = c >> 4, s8 = (c & 15) * 8;
        *(uint4*)(Eg + (size_t)row * LS + s8) = *(const uint4*)(Et + row * 136 + s8);
    }
}

// =====================================================================
// pv: wctx[128q][512d-half] = (E . ctx^T) * (1/rowsum(E)); rowss partials.
// Grid 256 = (b x 2 dh), XCD-swizzled. 512 thr, 8 waves 2q x 4d.
// B staged DIRECTLY from fp32 ctx via in-LDS transpose into padded
// Bs[64][264]. Reg-prefetch per dt.
// =====================================================================
__global__ __launch_bounds__(512) void pv_kernel(
    const ushort* __restrict__ E, const float* __restrict__ ctx,
    ushort* __restrict__ wctx, float* __restrict__ rowssP)
{
    const int bid = blockIdx.x;
    const int xcd = bid & 7, idx = bid >> 3;
    const int b  = xcd * 16 + (idx >> 1);
    const int dh = idx & 1;
    const int dglob0 = dh * 512;

    __shared__ ushort Es[128 * 256];       // 64 KB swz512
    __shared__ ushort Bs[64 * 264];        // 33 KB padded [d][s+8]
    __shared__ float rsumL[128];
    __shared__ float rinv[128];
    __shared__ float rowssL[128][4];

    const int t = threadIdx.x;
    const int wv = t >> 6, l = t & 63;
    const int wq = wv >> 2, wd = wv & 3;

    // ---- stage E (128q x 256s) + per-row exp sums ----
    const ushort* Eb = E + (size_t)b * LQ * LS;
    const int cc = t & 31, rr = t >> 5;    // col-chunk, row-base
    float part[8];
#pragma unroll
    for (int p = 0; p < 8; ++p) {
        int row = rr + p * 16;
        uint4 v = *(const uint4*)(Eb + (size_t)row * LS + cc * 8);
        *(uint4*)((char*)Es + swz512(row, cc * 16)) = v;
        const ushort* us = (const ushort*)&v;
        float s = 0.f;
#pragma unroll
        for (int j = 0; j < 8; ++j) s += bf2f(us[j]);
        part[p] = s;
    }
    rowssL[t >> 2][t & 3] = 0.f;
#pragma unroll
    for (int p = 0; p < 8; ++p) {
        float s = part[p];
        s += __shfl_xor(s, 1);  s += __shfl_xor(s, 2);
        s += __shfl_xor(s, 4);  s += __shfl_xor(s, 8);
        s += __shfl_xor(s, 16);
        if ((l & 31) == 0) rsumL[rr + p * 16] = s;
    }

    // ---- prefetch ctx tile dt=0 (coalesced float4 rows) ----
    const float* Cb = ctx + (size_t)b * LS * D + dglob0;
    const int sr = t >> 4, c4 = (t & 15) * 4;   // staging: s-row base, d-col
    float4 cr[8];
#pragma unroll
    for (int p = 0; p < 8; ++p)
        cr[p] = *(const float4*)(Cb + (size_t)(p * 32 + sr) * D + c4);

    __syncthreads();   // Es + rsumL visible
    if (t < 128) rinv[t] = 1.0f / rsumL[t];

    // ---- write Bs dt=0 (transpose scatter into padded tile) ----
#pragma unroll
    for (int p = 0; p < 8; ++p) {
        int s = p * 32 + sr;
        Bs[(c4 + 0) * 264 + s] = f2bf(cr[p].x);
        Bs[(c4 + 1) * 264 + s] = f2bf(cr[p].y);
        Bs[(c4 + 2) * 264 + s] = f2bf(cr[p].z);
        Bs[(c4 + 3) * 264 + s] = f2bf(cr[p].w);
    }
    __syncthreads();   // Bs + rinv visible

    ushort* Ob = wctx + (size_t)b * LQ * D + dglob0;

#pragma unroll 1
    for (int dt = 0; dt < 8; ++dt) {
        // issue next-tile loads (hide under MFMA)
        if (dt < 7) {
#pragma unroll
            for (int p = 0; p < 8; ++p)
                cr[p] = *(const float4*)(Cb + (size_t)(p * 32 + sr) * D + (dt + 1) * 64 + c4);
        }
        // MFMA: out rows wq*64+i*16.., cols dt*64 + wd*16..
        f32x4 acc[4] = {};
#pragma unroll
        for (int kk = 0; kk < 8; ++kk) {
            const ushort* bp = Bs + (wd * 16 + (l & 15)) * 264 + kk * 32 + (l >> 4) * 8;
            bf16x8 bfr = *(const bf16x8*)bp;
#pragma unroll
            for (int i = 0; i < 4; ++i) {
                bf16x8 af = *(const bf16x8*)((const char*)Es +
                    swz512(wq * 64 + i * 16 + (l & 15), kk * 64 + (l >> 4) * 16));
                acc[i] = mfma16(af, bfr, acc[i]);
            }
        }
        // epilogue: normalize, rowss partial, write
#pragma unroll
        for (int i = 0; i < 4; ++i)
#pragma unroll
            for (int r = 0; r < 4; ++r) {
                int row = wq * 64 + i * 16 + (l >> 4) * 4 + r;
                float wval = acc[i][r] * rinv[row];
                float p2 = wval * wval;
                p2 += __shfl_xor(p2, 1); p2 += __shfl_xor(p2, 2);
                p2 += __shfl_xor(p2, 4); p2 += __shfl_xor(p2, 8);
                if ((l & 15) == 0) rowssL[row][wd] += p2;
                Ob[(size_t)row * D + dt * 64 + wd * 16 + (l & 15)] = f2bf(wval);
            }
        __syncthreads();   // Bs consumed
        if (dt < 7) {
#pragma unroll
            for (int p = 0; p < 8; ++p) {
                int s = p * 32 + sr;
                Bs[(c4 + 0) * 264 + s] = f2bf(cr[p].x);
                Bs[(c4 + 1) * 264 + s] = f2bf(cr[p].y);
                Bs[(c4 + 2) * 264 + s] = f2bf(cr[p].z);
                Bs[(c4 + 3) * 264 + s] = f2bf(cr[p].w);
            }
            __syncthreads();
        }
    }
    if (t < 128)
        rowssP[(size_t)b * 256 + dh * 128 + t] =
            rowssL[t][0] + rowssL[t][1] + rowssL[t][2] + rowssL[t][3];
}

// =====================================================================
// gemm3+finalnorm: out[b][q][k] = l2norm_k( sum_d sr[q][d]*Wb[k][d] + b[k] )
// sr on the fly: (query - wctx*invq)^2 with invq from rowssP halves.
// BM=64(q) BN=256 BK=64. 512 thr, 8 waves 2x4.
// =====================================================================
__global__ __launch_bounds__(512) void gemm3_kernel(
    const ushort* __restrict__ wctx, const float* __restrict__ query,
    const float* __restrict__ rowssP, const ushort* __restrict__ Wb,
    const float* __restrict__ bias, float* __restrict__ out)
{
    const int m0 = blockIdx.x * 64;
    const int b  = blockIdx.y;
    __shared__ ushort As[64 * 64];
    __shared__ ushort Bs[256 * 64];
    __shared__ float red[64][4];
    __shared__ float invr[64];
    const int t = threadIdx.x;
    const int w = t >> 6, l = t & 63;
    const int wm = (w >> 2) * 32, wn = (w & 3) * 64;

    const int arow = t >> 3, ako = (t & 7) * 8;
    const float r0v = rowssP[(size_t)b * 256 + m0 + arow];
    const float r1v = rowssP[(size_t)b * 256 + 128 + m0 + arow];
    const float ivq = 1.0f / (sqrtf(r0v + r1v) + EPS);
    const float* Qp  = query + ((size_t)b * LQ + m0 + arow) * D + ako;
    const ushort* Wp = wctx  + ((size_t)b * LQ + m0 + arow) * D + ako;

    f32x4 acc[2][4] = {};

    for (int k0 = 0; k0 < D; k0 += 64) {
        if (k0) __syncthreads();
        {   // A: sr on the fly
            uint4 wu = *(const uint4*)(Wp + k0);
            float4 q1 = *(const float4*)(Qp + k0);
            float4 q2 = *(const float4*)(Qp + k0 + 4);
            float d0 = q1.x - bf2f((ushort)(wu.x & 0xffff)) * ivq;
            float d1 = q1.y - bf2f((ushort)(wu.x >> 16))    * ivq;
            float d2 = q1.z - bf2f((ushort)(wu.y & 0xffff)) * ivq;
            float d3 = q1.w - bf2f((ushort)(wu.y >> 16))    * ivq;
            float d4 = q2.x - bf2f((ushort)(wu.z & 0xffff)) * ivq;
            float d5 = q2.y - bf2f((ushort)(wu.z >> 16))    * ivq;
            float d6 = q2.z - bf2f((ushort)(wu.w & 0xffff)) * ivq;
            float d7 = q2.w - bf2f((ushort)(wu.w >> 16))    * ivq;
            float4 s1{d0*d0, d1*d1, d2*d2, d3*d3};
            float4 s2{d4*d4, d5*d5, d6*d6, d7*d7};
            *(uint4*)((char*)As + swz(arow, ako * 2)) = pack8(s1, s2);
        }
#pragma unroll
        for (int j = 0; j < 4; ++j) {   // B: Wb
            int c = t + j * 512;
            int row = c >> 3, ko = (c & 7) * 8;
            *(uint4*)((char*)Bs + swz(row, ko * 2)) =
                *(const uint4*)(Wb + (size_t)row * D + k0 + ko);
        }
        __syncthreads();
#pragma unroll
        for (int kk = 0; kk < 2; ++kk) {
            bf16x8 af[2], bfr[4];
#pragma unroll
            for (int i = 0; i < 2; ++i) af[i] = lds_frag(As, wm + i * 16 + (l & 15), kk, l);
#pragma unroll
            for (int n = 0; n < 4; ++n) bfr[n] = lds_frag(Bs, wn + n * 16 + (l & 15), kk, l);
#pragma unroll
            for (int i = 0; i < 2; ++i)
#pragma unroll
                for (int n = 0; n < 4; ++n) acc[i][n] = mfma16(af[i], bfr[n], acc[i][n]);
        }
    }
#pragma unroll
    for (int n = 0; n < 4; ++n) {
        float bv = bias[wn + n * 16 + (l & 15)];
#pragma unroll
        for (int i = 0; i < 2; ++i)
#pragma unroll
            for (int r = 0; r < 4; ++r) acc[i][n][r] += bv;
    }
#pragma unroll
    for (int i = 0; i < 2; ++i)
#pragma unroll
        for (int r = 0; r < 4; ++r) {
            float p = 0.f;
#pragma unroll
            for (int n = 0; n < 4; ++n) p += acc[i][n][r] * acc[i][n][r];
#pragma unroll
            for (int off = 1; off < 16; off <<= 1) p += __shfl_xor(p, off);
            int rowl = wm + i * 16 + (l >> 4) * 4 + r;
            if ((l & 15) == 0) red[rowl][w & 3] = p;
        }
    __syncthreads();
    if (t < 64) {
        float s = red[t][0] + red[t][1] + red[t][2] + red[t][3];
        invr[t] = 1.0f / (sqrtf(s) + EPS);
    }
    __syncthreads();
    float* Ob = out + ((size_t)b * LQ + m0) * SD;
#pragma unroll
    for (int i = 0; i < 2; ++i)
#pragma unroll
        for (int r = 0; r < 4; ++r) {
            int rowl = wm + i * 16 + (l >> 4) * 4 + r;
            float iv = invr[rowl];
#pragma unroll
            for (int n = 0; n < 4; ++n) {
                int col = wn + n * 16 + (l & 15);
                Ob[(size_t)rowl * SD + col] = acc[i][n][r] * iv;
            }
        }
}

// =====================================================================
extern "C" void kernel_launch(void* const* d_in, const int* in_sizes, int n_in,
                              void* d_out, int out_size, void* d_ws, size_t ws_size,
                              hipStream_t stream)
{
    const float* query  = (const float*)d_in[0];
    const float* ctx    = (const float*)d_in[1];
    const float* mat    = (const float*)d_in[2];
    const float* W      = (const float*)d_in[3];
    const float* bias   = (const float*)d_in[4];
    const int*   smooth = (const int*)d_in[5];
    float* out = (float*)d_out;

    char* ws = (char*)d_ws;
    ushort* wctx   = (ushort*)ws;                                   // 32 MiB
    ushort* E      = (ushort*)(ws + (size_t)32 * 1024 * 1024);      //  8 MiB
    ushort* Wb     = (ushort*)(ws + (size_t)40 * 1024 * 1024);      // 0.5 MiB
    float*  rowssP = (float*)(ws + (size_t)(40 * 1024 + 512) * 1024); // 128 KiB

    wconv_kernel<<<dim3(SD * D / (256 * 8)), 256, 0, stream>>>(W, Wb);
    gemmA_kernel<<<dim3(256), 512, 0, stream>>>(query, mat, ctx, smooth, E);
    pv_kernel<<<dim3(256), 512, 0, stream>>>(E, ctx, wctx, rowssP);
    gemm3_kernel<<<dim3(2, B), 512, 0, stream>>>(wctx, query, rowssP, Wb, bias, out);
}

// Round 11
// 149.761 us; speedup vs baseline: 1.1858x; 1.0029x over previous
//
#include <hip/hip_runtime.h>
#include <hip/hip_bf16.h>

constexpr int B  = 128;
constexpr int LQ = 128;
constexpr int LS = 256;
constexpr int D  = 1024;
constexpr int SD = 256;
constexpr float EPS = 1e-8f;

typedef __attribute__((ext_vector_type(8))) __bf16 bf16x8;
typedef __attribute__((ext_vector_type(4))) float f32x4;

__device__ inline ushort f2bf(float f) {
    union { float f; uint u; } v{f};
    uint r = v.u + 0x7fffu + ((v.u >> 16) & 1u);   // RNE
    return (ushort)(r >> 16);
}
__device__ inline float bf2f(ushort u) {
    union { uint u; float f; } v{(uint)u << 16};
    return v.f;
}
__device__ inline uint4 pack8(float4 a, float4 b) {
    union { ushort us[8]; uint4 u4; } r;
    r.us[0]=f2bf(a.x); r.us[1]=f2bf(a.y); r.us[2]=f2bf(a.z); r.us[3]=f2bf(a.w);
    r.us[4]=f2bf(b.x); r.us[5]=f2bf(b.y); r.us[6]=f2bf(b.z); r.us[7]=f2bf(b.w);
    return r.u4;
}
// 128B-row LDS tiles (64 bf16): XOR-swizzle bank fix
__device__ inline int swz(int row, int kbyte) {
    return row * 128 + (kbyte ^ ((row & 7) << 4));
}
__device__ inline bf16x8 lds_frag(const ushort* base, int row, int kk, int lane) {
    int kbyte = kk * 64 + (lane >> 4) * 16;
    return *(const bf16x8*)((const char*)base + swz(row, kbyte));
}
// 512B-row LDS tiles (256 bf16): same XOR pattern
__device__ inline int swz512(int row, int kbyte) {
    return row * 512 + (kbyte ^ ((row & 7) << 4));
}
__device__ inline f32x4 mfma16(bf16x8 a, bf16x8 b, f32x4 c) {
    return __builtin_amdgcn_mfma_f32_16x16x32_bf16(a, b, c, 0, 0, 0);
}

// =====================================================================
// Wb (bf16) <- W fp32
// =====================================================================
__global__ __launch_bounds__(256) void wconv_kernel(
    const float* __restrict__ W, ushort* __restrict__ Wb)
{
    size_t i = ((size_t)blockIdx.x * 256 + threadIdx.x) * 8;
    float4 a = *(const float4*)(W + i);
    float4 b = *(const float4*)(W + i + 4);
    *(uint4*)(Wb + i) = pack8(a, b);
}

// =====================================================================
// gemmA: per block (b, s-half of 128):
//   A-stage: qm = query*matrix fp32 -> bf16 (fused)
//   S = leaky(qm . ctx^T); col-l2norm over q (all 128 in-block);
//   E = exp(S*inv*smooth) bf16 (LDS-gathered, coalesced store).
// Grid 256 = (b x 2 s-halves), XCD-swizzled. 512 thr, 8 waves 2q x 4s.
// BM=128 BN=128 BK=64, double-buffered LDS (64 KB).
// __launch_bounds__(512,2): 67KB LDS admits only 1 block/CU (8 waves),
// so target 2 waves/EU -> 256-VGPR budget -> all 12 K-step loads stay
// in flight (at (512,1-default-8w) compiler capped VGPR=60 and
// serialized the loads -> 107us stall-bound plateau).
// =====================================================================
__global__ __launch_bounds__(512, 2) void gemmA_kernel(
    const float* __restrict__ query, const float* __restrict__ mat,
    const float* __restrict__ ctx, const int* __restrict__ smooth_p,
    ushort* __restrict__ E)
{
    const int bid = blockIdx.x;            // 256 blocks
    const int xcd = bid & 7, idx = bid >> 3;
    const int b  = xcd * 16 + (idx >> 1);
    const int n0 = (idx & 1) * 128;        // s-offset
    __shared__ ushort SH[4][128 * 64];     // As0,As1,Bs0,Bs1 (64 KB)
    __shared__ float colssP[2][128];
    __shared__ float invsm[128];
    ushort* Et = &SH[0][0];                // epilogue alias: 128 x 136

    const int t = threadIdx.x;
    const int wv = t >> 6, l = t & 63;
    const int wq = wv >> 2, wsv = wv & 3;

    const float* Qb = query + (size_t)b * LQ * D;
    const float* Mb = mat   + (size_t)b * LQ * D;
    const float* Cb = ctx   + ((size_t)b * LS + n0) * D;
    const int r0 = t >> 3, k8 = (t & 7) * 8;

    f32x4 acc[4][2] = {};
    float4 q0,q1,q2,q3, m0,m1,m2,m3, c0,c1,c2,c3;

    // ---- load tile k0 into registers ----
    auto loadT = [&](int k0) {
        const float* qp = Qb + (size_t)r0 * D + k0 + k8;
        const float* mp = Mb + (size_t)r0 * D + k0 + k8;
        q0 = *(const float4*)qp; q1 = *(const float4*)(qp + 4);
        m0 = *(const float4*)mp; m1 = *(const float4*)(mp + 4);
        qp += (size_t)64 * D;  mp += (size_t)64 * D;
        q2 = *(const float4*)qp; q3 = *(const float4*)(qp + 4);
        m2 = *(const float4*)mp; m3 = *(const float4*)(mp + 4);
        const float* cp = Cb + (size_t)r0 * D + k0 + k8;
        c0 = *(const float4*)cp; c1 = *(const float4*)(cp + 4);
        cp += (size_t)64 * D;
        c2 = *(const float4*)cp; c3 = *(const float4*)(cp + 4);
    };
    // ---- pack + store registers into LDS buffer ----
    auto storeT = [&](int buf) {
        float4 p1{q0.x*m0.x, q0.y*m0.y, q0.z*m0.z, q0.w*m0.w};
        float4 p2{q1.x*m1.x, q1.y*m1.y, q1.z*m1.z, q1.w*m1.w};
        *(uint4*)((char*)&SH[buf][0] + swz(r0, k8 * 2)) = pack8(p1, p2);
        float4 p3{q2.x*m2.x, q2.y*m2.y, q2.z*m2.z, q2.w*m2.w};
        float4 p4{q3.x*m3.x, q3.y*m3.y, q3.z*m3.z, q3.w*m3.w};
        *(uint4*)((char*)&SH[buf][0] + swz(r0 + 64, k8 * 2)) = pack8(p3, p4);
        *(uint4*)((char*)&SH[2 + buf][0] + swz(r0, k8 * 2))      = pack8(c0, c1);
        *(uint4*)((char*)&SH[2 + buf][0] + swz(r0 + 64, k8 * 2)) = pack8(c2, c3);
    };
    // ---- MFMA on buffer ----
    auto mfmaT = [&](int buf) {
#pragma unroll
        for (int kk = 0; kk < 2; ++kk) {
            bf16x8 bfr0 = lds_frag(&SH[2 + buf][0], wsv * 32 + (l & 15), kk, l);
            bf16x8 bfr1 = lds_frag(&SH[2 + buf][0], wsv * 32 + 16 + (l & 15), kk, l);
#pragma unroll
            for (int i = 0; i < 4; ++i) {
                bf16x8 af = lds_frag(&SH[buf][0], wq * 64 + i * 16 + (l & 15), kk, l);
                acc[i][0] = mfma16(af, bfr0, acc[i][0]);
                acc[i][1] = mfma16(af, bfr1, acc[i][1]);
            }
        }
    };

    loadT(0);
    storeT(0);
    __syncthreads();
    int cur = 0;
#pragma unroll 1
    for (int ks = 0; ks < 15; ++ks) {
        loadT((ks + 1) * 64);
        mfmaT(cur);
        storeT(cur ^ 1);
        __syncthreads();
        cur ^= 1;
    }
    mfmaT(cur);

    // ---- epilogue: leaky + col sumsq -> invsm -> E = exp ----
#pragma unroll
    for (int n = 0; n < 2; ++n) {
        float csum = 0.f;
#pragma unroll
        for (int i = 0; i < 4; ++i)
#pragma unroll
            for (int r = 0; r < 4; ++r) {
                float v = acc[i][n][r];
                v = v >= 0.f ? v : 0.1f * v;
                acc[i][n][r] = v;
                csum += v * v;
            }
        csum += __shfl_xor(csum, 16);
        csum += __shfl_xor(csum, 32);
        if (l < 16) colssP[wq][wsv * 32 + n * 16 + l] = csum;
    }
    __syncthreads();   // also: all MFMA reads done -> SH reusable as Et
    const float sm = (float)(*smooth_p);
    if (t < 128) invsm[t] = sm / (sqrtf(colssP[0][t] + colssP[1][t]) + EPS);
    __syncthreads();
#pragma unroll
    for (int n = 0; n < 2; ++n) {
        const float invc = invsm[wsv * 32 + n * 16 + (l & 15)];
#pragma unroll
        for (int i = 0; i < 4; ++i)
#pragma unroll
            for (int r = 0; r < 4; ++r) {
                int row = wq * 64 + i * 16 + (l >> 4) * 4 + r;
                Et[row * 136 + wsv * 32 + n * 16 + (l & 15)] =
                    f2bf(__expf(acc[i][n][r] * invc));
            }
    }
    __syncthreads();
    // coalesced E store: 128 rows x 16 uint4 chunks = 2048, 4/thread
    ushort* Eg = E + (size_t)b * LQ * LS + n0;
#pragma unroll
    for (int j = 0; j < 4; ++j) {
        int c = t + j * 512;
        int row = c >> 4, s8 = (c & 15) * 8;
        *(uint4*)(Eg + (size_t)row * LS + s8) = *(const uint4*)(Et + row * 136 + s8);
    }
}

// =====================================================================
// pv: wctx[128q][512d-half] = (E . ctx^T) * (1/rowsum(E)); rowss partials.
// Grid 256 = (b x 2 dh), XCD-swizzled. 512 thr, 8 waves 2q x 4d.
// B staged DIRECTLY from fp32 ctx via in-LDS transpose into padded
// Bs[64][264]. Reg-prefetch per dt. (512,2): 97KB LDS -> 1 block/CU.
// =====================================================================
__global__ __launch_bounds__(512, 2) void pv_kernel(
    const ushort* __restrict__ E, const float* __restrict__ ctx,
    ushort* __restrict__ wctx, float* __restrict__ rowssP)
{
    const int bid = blockIdx.x;
    const int xcd = bid & 7, idx = bid >> 3;
    const int b  = xcd * 16 + (idx >> 1);
    const int dh = idx & 1;
    const int dglob0 = dh * 512;

    __shared__ ushort Es[128 * 256];       // 64 KB swz512
    __shared__ ushort Bs[64 * 264];        // 33 KB padded [d][s+8]
    __shared__ float rsumL[128];
    __shared__ float rinv[128];
    __shared__ float rowssL[128][4];

    const int t = threadIdx.x;
    const int wv = t >> 6, l = t & 63;
    const int wq = wv >> 2, wd = wv & 3;

    // ---- stage E (128q x 256s) + per-row exp sums ----
    const ushort* Eb = E + (size_t)b * LQ * LS;
    const int cc = t & 31, rr = t >> 5;    // col-chunk, row-base
    float part[8];
#pragma unroll
    for (int p = 0; p < 8; ++p) {
        int row = rr + p * 16;
        uint4 v = *(const uint4*)(Eb + (size_t)row * LS + cc * 8);
        *(uint4*)((char*)Es + swz512(row, cc * 16)) = v;
        const ushort* us = (const ushort*)&v;
        float s = 0.f;
#pragma unroll
        for (int j = 0; j < 8; ++j) s += bf2f(us[j]);
        part[p] = s;
    }
    rowssL[t >> 2][t & 3] = 0.f;
#pragma unroll
    for (int p = 0; p < 8; ++p) {
        float s = part[p];
        s += __shfl_xor(s, 1);  s += __shfl_xor(s, 2);
        s += __shfl_xor(s, 4);  s += __shfl_xor(s, 8);
        s += __shfl_xor(s, 16);
        if ((l & 31) == 0) rsumL[rr + p * 16] = s;
    }

    // ---- prefetch ctx tile dt=0 (coalesced float4 rows) ----
    const float* Cb = ctx + (size_t)b * LS * D + dglob0;
    const int sr = t >> 4, c4 = (t & 15) * 4;   // staging: s-row base, d-col
    float4 cr[8];
#pragma unroll
    for (int p = 0; p < 8; ++p)
        cr[p] = *(const float4*)(Cb + (size_t)(p * 32 + sr) * D + c4);

    __syncthreads();   // Es + rsumL visible
    if (t < 128) rinv[t] = 1.0f / rsumL[t];

    // ---- write Bs dt=0 (transpose scatter into padded tile) ----
#pragma unroll
    for (int p = 0; p < 8; ++p) {
        int s = p * 32 + sr;
        Bs[(c4 + 0) * 264 + s] = f2bf(cr[p].x);
        Bs[(c4 + 1) * 264 + s] = f2bf(cr[p].y);
        Bs[(c4 + 2) * 264 + s] = f2bf(cr[p].z);
        Bs[(c4 + 3) * 264 + s] = f2bf(cr[p].w);
    }
    __syncthreads();   // Bs + rinv visible

    ushort* Ob = wctx + (size_t)b * LQ * D + dglob0;

#pragma unroll 1
    for (int dt = 0; dt < 8; ++dt) {
        // issue next-tile loads (hide under MFMA)
        if (dt < 7) {
#pragma unroll
            for (int p = 0; p < 8; ++p)
                cr[p] = *(const float4*)(Cb + (size_t)(p * 32 + sr) * D + (dt + 1) * 64 + c4);
        }
        // MFMA: out rows wq*64+i*16.., cols dt*64 + wd*16..
        f32x4 acc[4] = {};
#pragma unroll
        for (int kk = 0; kk < 8; ++kk) {
            const ushort* bp = Bs + (wd * 16 + (l & 15)) * 264 + kk * 32 + (l >> 4) * 8;
            bf16x8 bfr = *(const bf16x8*)bp;
#pragma unroll
            for (int i = 0; i < 4; ++i) {
                bf16x8 af = *(const bf16x8*)((const char*)Es +
                    swz512(wq * 64 + i * 16 + (l & 15), kk * 64 + (l >> 4) * 16));
                acc[i] = mfma16(af, bfr, acc[i]);
            }
        }
        // epilogue: normalize, rowss partial, write
#pragma unroll
        for (int i = 0; i < 4; ++i)
#pragma unroll
            for (int r = 0; r < 4; ++r) {
                int row = wq * 64 + i * 16 + (l >> 4) * 4 + r;
                float wval = acc[i][r] * rinv[row];
                float p2 = wval * wval;
                p2 += __shfl_xor(p2, 1); p2 += __shfl_xor(p2, 2);
                p2 += __shfl_xor(p2, 4); p2 += __shfl_xor(p2, 8);
                if ((l & 15) == 0) rowssL[row][wd] += p2;
                Ob[(size_t)row * D + dt * 64 + wd * 16 + (l & 15)] = f2bf(wval);
            }
        __syncthreads();   // Bs consumed
        if (dt < 7) {
#pragma unroll
            for (int p = 0; p < 8; ++p) {
                int s = p * 32 + sr;
                Bs[(c4 + 0) * 264 + s] = f2bf(cr[p].x);
                Bs[(c4 + 1) * 264 + s] = f2bf(cr[p].y);
                Bs[(c4 + 2) * 264 + s] = f2bf(cr[p].z);
                Bs[(c4 + 3) * 264 + s] = f2bf(cr[p].w);
            }
            __syncthreads();
        }
    }
    if (t < 128)
        rowssP[(size_t)b * 256 + dh * 128 + t] =
            rowssL[t][0] + rowssL[t][1] + rowssL[t][2] + rowssL[t][3];
}

// =====================================================================
// gemm3+finalnorm: out[b][q][k] = l2norm_k( sum_d sr[q][d]*Wb[k][d] + b[k] )
// sr on the fly: (query - wctx*invq)^2 with invq from rowssP halves.
// BM=64(q) BN=256 BK=64. 512 thr, 8 waves 2x4. (512,2) reg budget.
// =====================================================================
__global__ __launch_bounds__(512, 2) void gemm3_kernel(
    const ushort* __restrict__ wctx, const float* __restrict__ query,
    const float* __restrict__ rowssP, const ushort* __restrict__ Wb,
    const float* __restrict__ bias, float* __restrict__ out)
{
    const int m0 = blockIdx.x * 64;
    const int b  = blockIdx.y;
    __shared__ ushort As[64 * 64];
    __shared__ ushort Bs[256 * 64];
    __shared__ float red[64][4];
    __shared__ float invr[64];
    const int t = threadIdx.x;
    const int w = t >> 6, l = t & 63;
    const int wm = (w >> 2) * 32, wn = (w & 3) * 64;

    const int arow = t >> 3, ako = (t & 7) * 8;
    const float r0v = rowssP[(size_t)b * 256 + m0 + arow];
    const float r1v = rowssP[(size_t)b * 256 + 128 + m0 + arow];
    const float ivq = 1.0f / (sqrtf(r0v + r1v) + EPS);
    const float* Qp  = query + ((size_t)b * LQ + m0 + arow) * D + ako;
    const ushort* Wp = wctx  + ((size_t)b * LQ + m0 + arow) * D + ako;

    f32x4 acc[2][4] = {};

    for (int k0 = 0; k0 < D; k0 += 64) {
        if (k0) __syncthreads();
        {   // A: sr on the fly
            uint4 wu = *(const uint4*)(Wp + k0);
            float4 q1 = *(const float4*)(Qp + k0);
            float4 q2 = *(const float4*)(Qp + k0 + 4);
            float d0 = q1.x - bf2f((ushort)(wu.x & 0xffff)) * ivq;
            float d1 = q1.y - bf2f((ushort)(wu.x >> 16))    * ivq;
            float d2 = q1.z - bf2f((ushort)(wu.y & 0xffff)) * ivq;
            float d3 = q1.w - bf2f((ushort)(wu.y >> 16))    * ivq;
            float d4 = q2.x - bf2f((ushort)(wu.z & 0xffff)) * ivq;
            float d5 = q2.y - bf2f((ushort)(wu.z >> 16))    * ivq;
            float d6 = q2.z - bf2f((ushort)(wu.w & 0xffff)) * ivq;
            float d7 = q2.w - bf2f((ushort)(wu.w >> 16))    * ivq;
            float4 s1{d0*d0, d1*d1, d2*d2, d3*d3};
            float4 s2{d4*d4, d5*d5, d6*d6, d7*d7};
            *(uint4*)((char*)As + swz(arow, ako * 2)) = pack8(s1, s2);
        }
#pragma unroll
        for (int j = 0; j < 4; ++j) {   // B: Wb
            int c = t + j * 512;
            int row = c >> 3, ko = (c & 7) * 8;
            *(uint4*)((char*)Bs + swz(row, ko * 2)) =
                *(const uint4*)(Wb + (size_t)row * D + k0 + ko);
        }
        __syncthreads();
#pragma unroll
        for (int kk = 0; kk < 2; ++kk) {
            bf16x8 af[2], bfr[4];
#pragma unroll
            for (int i = 0; i < 2; ++i) af[i] = lds_frag(As, wm + i * 16 + (l & 15), kk, l);
#pragma unroll
            for (int n = 0; n < 4; ++n) bfr[n] = lds_frag(Bs, wn + n * 16 + (l & 15), kk, l);
#pragma unroll
            for (int i = 0; i < 2; ++i)
#pragma unroll
                for (int n = 0; n < 4; ++n) acc[i][n] = mfma16(af[i], bfr[n], acc[i][n]);
        }
    }
#pragma unroll
    for (int n = 0; n < 4; ++n) {
        float bv = bias[wn + n * 16 + (l & 15)];
#pragma unroll
        for (int i = 0; i < 2; ++i)
#pragma unroll
            for (int r = 0; r < 4; ++r) acc[i][n][r] += bv;
    }
#pragma unroll
    for (int i = 0; i < 2; ++i)
#pragma unroll
        for (int r = 0; r < 4; ++r) {
            float p = 0.f;
#pragma unroll
            for (int n = 0; n < 4; ++n) p += acc[i][n][r] * acc[i][n][r];
#pragma unroll
            for (int off = 1; off < 16; off <<= 1) p += __shfl_xor(p, off);
            int rowl = wm + i * 16 + (l >> 4) * 4 + r;
            if ((l & 15) == 0) red[rowl][w & 3] = p;
        }
    __syncthreads();
    if (t < 64) {
        float s = red[t][0] + red[t][1] + red[t][2] + red[t][3];
        invr[t] = 1.0f / (sqrtf(s) + EPS);
    }
    __syncthreads();
    float* Ob = out + ((size_t)b * LQ + m0) * SD;
#pragma unroll
    for (int i = 0; i < 2; ++i)
#pragma unroll
        for (int r = 0; r < 4; ++r) {
            int rowl = wm + i * 16 + (l >> 4) * 4 + r;
            float iv = invr[rowl];
#pragma unroll
            for (int n = 0; n < 4; ++n) {
                int col = wn + n * 16 + (l & 15);
                Ob[(size_t)rowl * SD + col] = acc[i][n][r] * iv;
            }
        }
}

// =====================================================================
extern "C" void kernel_launch(void* const* d_in, const int* in_sizes, int n_in,
                              void* d_out, int out_size, void* d_ws, size_t ws_size,
                              hipStream_t stream)
{
    const float* query  = (const float*)d_in[0];
    const float* ctx    = (const float*)d_in[1];
    const float* mat    = (const float*)d_in[2];
    const float* W      = (const float*)d_in[3];
    const float* bias   = (const float*)d_in[4];
    const int*   smooth = (const int*)d_in[5];
    float* out = (float*)d_out;

    char* ws = (char*)d_ws;
    ushort* wctx   = (ushort*)ws;                                   // 32 MiB
    ushort* E      = (ushort*)(ws + (size_t)32 * 1024 * 1024);      //  8 MiB
    ushort* Wb     = (ushort*)(ws + (size_t)40 * 1024 * 1024);      // 0.5 MiB
    float*  rowssP = (float*)(ws + (size_t)(40 * 1024 + 512) * 1024); // 128 KiB

    wconv_kernel<<<dim3(SD * D / (256 * 8)), 256, 0, stream>>>(W, Wb);
    gemmA_kernel<<<dim3(256), 512, 0, stream>>>(query, mat, ctx, smooth, E);
    pv_kernel<<<dim3(256), 512, 0, stream>>>(E, ctx, wctx, rowssP);
    gemm3_kernel<<<dim3(2, B), 512, 0, stream>>>(wctx, query, rowssP, Wb, bias, out);
}